// Round 5
// baseline (434.140 us; speedup 1.0000x reference)
//
#include <hip/hip_runtime.h>

// Problem constants
#define BB   16
#define NQ   1024
#define NK   2048
#define DD   512
#define VV   512
#define OO   256
#define SCALE 0.044194173824159216f  // 1/sqrt(512)

typedef __attribute__((ext_vector_type(4))) float f32x4;
typedef __attribute__((ext_vector_type(8))) short s16x8;

#define AS1(p) ((const __attribute__((address_space(1))) void*)(p))
#define AS3(p) ((__attribute__((address_space(3))) void*)(p))

__device__ __forceinline__ unsigned short f2bf(float f) {
  unsigned u = __float_as_uint(f);
  u += 0x7fffu + ((u >> 16) & 1u);   // round-to-nearest-even (finite inputs)
  return (unsigned short)(u >> 16);
}
__device__ __forceinline__ float bf2f(unsigned short b) {
  return __uint_as_float(((unsigned)b) << 16);
}

#define MFMA16(a, b, c) __builtin_amdgcn_mfma_f32_16x16x32_bf16(a, b, c, 0, 0, 0)

// ---------------------------------------------------------------------------
// Core: C(128x128) = A(128xK) * B(128xK)^T in bf16 MFMA, m97 two-barrier
// structure (measured best: R4's explicit dbuf regressed 108->121 us).
// ---------------------------------------------------------------------------
__device__ __forceinline__ void gemm_bt_core(
    const unsigned short* __restrict__ Abase,
    const unsigned short* __restrict__ Bbase,
    int K,
    unsigned short* As, unsigned short* Bs,   // [128*32] each (8 KB each)
    f32x4 acc[4][4])
{
  const int t = threadIdx.x;
  const int w = t >> 6;
  const int l = t & 63;
  const int srow = l >> 2;
  const int scol = (l & 3) * 8;
  const int r0 = (w * 2 + 0) * 16 + srow;
  const int r1 = (w * 2 + 1) * 16 + srow;
  const int lds0 = (w * 2 + 0) * 512 + l * 8;
  const int lds1 = (w * 2 + 1) * 512 + l * 8;
  const int wm = (w >> 1) * 64;
  const int wn = (w & 1) * 64;
  const int lm = l & 15;
  const int lq = l >> 4;

  for (int kt = 0; kt < K; kt += 32) {
    __builtin_amdgcn_global_load_lds(AS1(Abase + (size_t)r0 * K + kt + scol), AS3(As + lds0), 16, 0, 0);
    __builtin_amdgcn_global_load_lds(AS1(Abase + (size_t)r1 * K + kt + scol), AS3(As + lds1), 16, 0, 0);
    __builtin_amdgcn_global_load_lds(AS1(Bbase + (size_t)r0 * K + kt + scol), AS3(Bs + lds0), 16, 0, 0);
    __builtin_amdgcn_global_load_lds(AS1(Bbase + (size_t)r1 * K + kt + scol), AS3(Bs + lds1), 16, 0, 0);
    __syncthreads();
    s16x8 af[4], bfr[4];
    #pragma unroll
    for (int i = 0; i < 4; ++i) {
      af[i]  = *(const s16x8*)(As + (wm + i * 16 + lm) * 32 + lq * 8);
      bfr[i] = *(const s16x8*)(Bs + (wn + i * 16 + lm) * 32 + lq * 8);
    }
    #pragma unroll
    for (int mi = 0; mi < 4; ++mi)
      #pragma unroll
      for (int ni = 0; ni < 4; ++ni)
        acc[mi][ni] = MFMA16(af[mi], bfr[ni], acc[mi][ni]);
    __syncthreads();
  }
}

// C/D layout (m89/m91): col = lane&15, row = (lane>>4)*4 + reg

#define CS_STRIDE 136   // shorts

// ---------------------------------------------------------------------------
// Merged kernel: blocks [0,2048) = QK tiles; blocks [2048,2560) = VW tiles:
// VWt[b,o,k] = sum_v V[b,k,v]*W[o,v] (transposed-epilogue NT GEMM).
// R6: XCD-chunked swizzle (2560 = 8 x 320, bijective); sums computed in pvw.
// UNCHANGED in R7 (control).
// ---------------------------------------------------------------------------
__global__ __launch_bounds__(256)
void qkvw_kernel(const unsigned short* __restrict__ Qb,
                 const unsigned short* __restrict__ Kb,
                 const unsigned short* __restrict__ Vb,
                 const unsigned short* __restrict__ Wb,
                 const int* __restrict__ mask,
                 unsigned short* __restrict__ P,
                 unsigned short* __restrict__ VWt)
{
  __shared__ unsigned short smem[128 * CS_STRIDE];   // 34.8 KB
  unsigned short* As = smem;
  unsigned short* Bs = smem + 4096;
  unsigned short* Cs = smem;
  const int bid0 = blockIdx.x;
  const int bid = (bid0 & 7) * 320 + (bid0 >> 3);    // XCD-chunked swizzle
  const int t = threadIdx.x, w = t >> 6, l = t & 63;
  const int wm = (w >> 1) * 64, wn = (w & 1) * 64;
  const int lm = l & 15, lq = l >> 4;
  const int trow = t >> 4, tcol = (t & 15) * 8;

  f32x4 acc[4][4];
  #pragma unroll
  for (int i = 0; i < 4; ++i)
    #pragma unroll
    for (int j = 0; j < 4; ++j) acc[i][j] = (f32x4){0.f, 0.f, 0.f, 0.f};

  if (bid < 2048) {
    // ---------------- QK path ----------------
    const int b  = bid >> 7;
    const int tm = (bid >> 4) & 7;
    const int tn = bid & 15;

    gemm_bt_core(Qb + ((size_t)b * NQ + tm * 128) * DD,
                 Kb + ((size_t)b * NK + tn * 128) * DD, DD, As, Bs, acc);

    #pragma unroll
    for (int mi = 0; mi < 4; ++mi)
      #pragma unroll
      for (int ni = 0; ni < 4; ++ni)
        #pragma unroll
        for (int r = 0; r < 4; ++r)
          Cs[(wm + mi * 16 + lq * 4 + r) * CS_STRIDE + wn + ni * 16 + lm] =
              f2bf(acc[mi][ni][r] * SCALE);
    __syncthreads();

    #pragma unroll
    for (int it = 0; it < 8; ++it) {
      const int row = it * 16 + trow;
      const int gq = tm * 128 + row;
      const size_t gbase = ((size_t)b * NQ + gq) * NK + tn * 128 + tcol;
      s16x8 v = *(const s16x8*)(Cs + row * CS_STRIDE + tcol);
      const int4 m0 = *(const int4*)(mask + gbase);
      const int4 m1 = *(const int4*)(mask + gbase + 4);
      s16x8 o;
      o[0] = m0.x ? (short)f2bf(__expf(bf2f((unsigned short)v[0]))) : (short)0;
      o[1] = m0.y ? (short)f2bf(__expf(bf2f((unsigned short)v[1]))) : (short)0;
      o[2] = m0.z ? (short)f2bf(__expf(bf2f((unsigned short)v[2]))) : (short)0;
      o[3] = m0.w ? (short)f2bf(__expf(bf2f((unsigned short)v[3]))) : (short)0;
      o[4] = m1.x ? (short)f2bf(__expf(bf2f((unsigned short)v[4]))) : (short)0;
      o[5] = m1.y ? (short)f2bf(__expf(bf2f((unsigned short)v[5]))) : (short)0;
      o[6] = m1.z ? (short)f2bf(__expf(bf2f((unsigned short)v[6]))) : (short)0;
      o[7] = m1.w ? (short)f2bf(__expf(bf2f((unsigned short)v[7]))) : (short)0;
      *(s16x8*)(P + gbase) = o;
    }
  } else {
    // ---------------- VW path: VWt[b, o, k] ---------
    const int vid = bid - 2048;
    const int b  = vid >> 5;
    const int kt = (vid >> 1) & 15;
    const int ot = vid & 1;

    gemm_bt_core(Vb + ((size_t)b * NK + kt * 128) * VV,
                 Wb + (size_t)ot * 128 * VV, VV, As, Bs, acc);

    // C[r=k_local][c=o_local]; scatter transposed: Cs[o_local][k_local]
    #pragma unroll
    for (int mi = 0; mi < 4; ++mi)
      #pragma unroll
      for (int ni = 0; ni < 4; ++ni)
        #pragma unroll
        for (int r = 0; r < 4; ++r)
          Cs[(wn + ni * 16 + lm) * CS_STRIDE + wm + mi * 16 + lq * 4 + r] =
              f2bf(acc[mi][ni][r]);
    __syncthreads();

    #pragma unroll
    for (int it = 0; it < 8; ++it) {
      const int orow = it * 16 + trow;   // o_local
      s16x8 v = *(const s16x8*)(Cs + orow * CS_STRIDE + tcol);
      *(s16x8*)(VWt + ((size_t)b * OO + ot * 128 + orow) * NK + kt * 128 + tcol) = v;
    }
  }
}

// ---------------------------------------------------------------------------
// pvw: out[b,q,o] = (sum_k P[b,q,k] * VWt[b,o,k]) / (sum_k P[b,q,k]) + bias[o]
// R7: tile 32q x 128o (was 64x128) -> grid 1024 blocks = 4/CU (was 2/CU);
// LDS 40 KB (2 bufs x (A 32x64 + B 128x64)). Latency-bound loop: more
// co-resident blocks = cross-block overlap of the staging drain (m114).
// 4 waves as 1x4 over o; BK=64 dbuf prefetch + XOR swizzle kept; row-sums
// via ones-MFMA kept (in-register normalization).
// ---------------------------------------------------------------------------
#define PW_STRIDE 132   // floats
__global__ __launch_bounds__(256)
void pvw_kernel(const unsigned short* __restrict__ P,
                const unsigned short* __restrict__ VWt,
                const float* __restrict__ bias,
                float* __restrict__ out)
{
  const int ot = blockIdx.x;   // 2
  const int qt = blockIdx.y;   // 32
  const int b  = blockIdx.z;   // 16
  __shared__ unsigned short smem[20480];   // 40 KB: 2 bufs x (A 32x64 + B 128x64)

  const int t = threadIdx.x, w = t >> 6, l = t & 63;
  const int lm = l & 15, lq = l >> 4;

  f32x4 acc[2][2];
  #pragma unroll
  for (int i = 0; i < 2; ++i)
    #pragma unroll
    for (int j = 0; j < 2; ++j) acc[i][j] = (f32x4){0.f, 0.f, 0.f, 0.f};
  f32x4 accS[2];
  accS[0] = (f32x4){0.f, 0.f, 0.f, 0.f};
  accS[1] = (f32x4){0.f, 0.f, 0.f, 0.f};
  s16x8 ones;
  #pragma unroll
  for (int j = 0; j < 8; ++j) ones[j] = (short)0x3F80;   // bf16 1.0

  const unsigned short* Abase = P   + ((size_t)b * NQ + qt * 32) * NK;
  const unsigned short* Bbase = VWt + ((size_t)b * OO + ot * 128) * NK;

  // staging: thread t loads 16B chunk (t&7) of row (t>>3); swizzled source
  // column = (chunk ^ (row&7)) so linear LDS dest holds swizzled data.
  const int srow = t >> 3;                               // 0..31
  const int ssc  = (((t & 7) ^ (srow & 7)) << 3);        // shorts

#define PV_STAGE(buf, k0v) do {                                                            \
    unsigned short* As_ = smem + (buf) * 10240;                                            \
    unsigned short* Bs_ = As_ + 2048;                                                      \
    const int k0_ = (k0v);                                                                 \
    __builtin_amdgcn_global_load_lds(AS1(Abase + (size_t)(srow     ) * NK + k0_ + ssc), AS3(As_ +        t * 8), 16, 0, 0); \
    __builtin_amdgcn_global_load_lds(AS1(Bbase + (size_t)(srow     ) * NK + k0_ + ssc), AS3(Bs_ +        t * 8), 16, 0, 0); \
    __builtin_amdgcn_global_load_lds(AS1(Bbase + (size_t)(srow + 32) * NK + k0_ + ssc), AS3(Bs_ + 2048 + t * 8), 16, 0, 0); \
    __builtin_amdgcn_global_load_lds(AS1(Bbase + (size_t)(srow + 64) * NK + k0_ + ssc), AS3(Bs_ + 4096 + t * 8), 16, 0, 0); \
    __builtin_amdgcn_global_load_lds(AS1(Bbase + (size_t)(srow + 96) * NK + k0_ + ssc), AS3(Bs_ + 6144 + t * 8), 16, 0, 0); \
  } while (0)

  PV_STAGE(0, 0);
  __syncthreads();
  for (int k0 = 0; k0 < NK; k0 += 64) {
    const int cur = (k0 >> 6) & 1;
    if (k0 + 64 < NK) PV_STAGE(cur ^ 1, k0 + 64);      // prefetch overlaps compute
    const unsigned short* As = smem + cur * 10240;
    const unsigned short* Bs = As + 2048;
    s16x8 af[2][2], bfr[2][2];
    #pragma unroll
    for (int mi = 0; mi < 2; ++mi) {
      const int row = mi * 16 + lm;                    // q_local row 0..31
      #pragma unroll
      for (int ks = 0; ks < 2; ++ks)
        af[mi][ks] = *(const s16x8*)(As + row * 64 + (((ks * 4 + lq) ^ (row & 7)) << 3));
    }
    #pragma unroll
    for (int ni = 0; ni < 2; ++ni) {
      const int row = w * 32 + ni * 16 + lm;           // o_local row 0..127
      #pragma unroll
      for (int ks = 0; ks < 2; ++ks)
        bfr[ni][ks] = *(const s16x8*)(Bs + row * 64 + (((ks * 4 + lq) ^ (row & 7)) << 3));
    }
    #pragma unroll
    for (int mi = 0; mi < 2; ++mi) {
      #pragma unroll
      for (int ni = 0; ni < 2; ++ni) {
        acc[mi][ni] = MFMA16(af[mi][0], bfr[ni][0], acc[mi][ni]);
        acc[mi][ni] = MFMA16(af[mi][1], bfr[ni][1], acc[mi][ni]);
      }
      accS[mi] = MFMA16(af[mi][0], ones, accS[mi]);    // row-sum (all cols equal)
      accS[mi] = MFMA16(af[mi][1], ones, accS[mi]);
    }
    __syncthreads();
  }
#undef PV_STAGE

  // epilogue: normalize in-register, via LDS, coalesced fp32 stores + bias
  float* Csf = (float*)smem;   // 32 x 132 floats = 16.9 KB <= 40 KB
  #pragma unroll
  for (int mi = 0; mi < 2; ++mi)
    #pragma unroll
    for (int r = 0; r < 4; ++r) {
      const float inv = 1.0f / accS[mi][r];
      const int row = mi * 16 + lq * 4 + r;                    // q_local
      #pragma unroll
      for (int ni = 0; ni < 2; ++ni) {
        const int col = w * 32 + ni * 16 + lm;                 // o_local
        Csf[row * PW_STRIDE + col] = acc[mi][ni][r] * inv;
      }
    }
  __syncthreads();
  const int trow = t >> 3;
  #pragma unroll
  for (int it = 0; it < 2; ++it) {
    const int col = (t & 7) * 8 + it * 64;
    f32x4 a = *(const f32x4*)(Csf + trow * PW_STRIDE + col);
    f32x4 c = *(const f32x4*)(Csf + trow * PW_STRIDE + col + 4);
    const int go = ot * 128 + col;
    a += *(const f32x4*)(bias + go);
    c += *(const f32x4*)(bias + go + 4);
    float* o = out + ((size_t)b * NQ + qt * 32 + trow) * OO + go;
    *(f32x4*)o = a;
    *(f32x4*)(o + 4) = c;
  }
}

// ---------------------------------------------------------------------------
// prep: fp32->bf16 converts (Q, K, V, W).
// R7: grid-stride, 2048 blocks x 256 threads (m13-verified streaming shape).
// All ranges are exact multiples of 524288 threads: Q=2, K=4, V=4 iters,
// W covered by first 16384 threads. No remainder divergence.
// ---------------------------------------------------------------------------
__device__ __forceinline__ void cvt8(const float* __restrict__ in,
                                     unsigned short* __restrict__ out, int i)
{
  const float4* p = (const float4*)in + (size_t)i * 2;
  const float4 a = p[0], b = p[1];
  s16x8 o;
  o[0] = (short)f2bf(a.x); o[1] = (short)f2bf(a.y);
  o[2] = (short)f2bf(a.z); o[3] = (short)f2bf(a.w);
  o[4] = (short)f2bf(b.x); o[5] = (short)f2bf(b.y);
  o[6] = (short)f2bf(b.z); o[7] = (short)f2bf(b.w);
  ((s16x8*)out)[i] = o;
}

#define PREP_NTH (2048 * 256)

__global__ __launch_bounds__(256)
void prep_kernel(const float* __restrict__ q, const float* __restrict__ k,
                 const float* __restrict__ v, const float* __restrict__ w,
                 unsigned short* __restrict__ Qb, unsigned short* __restrict__ Kb,
                 unsigned short* __restrict__ Vb, unsigned short* __restrict__ Wb)
{
  const int tid = blockIdx.x * 256 + threadIdx.x;
  // Q: 1,048,576 groups = 2 * PREP_NTH
  #pragma unroll
  for (int it = 0; it < 2; ++it) cvt8(q, Qb, tid + it * PREP_NTH);
  // K: 2,097,152 groups = 4 * PREP_NTH
  #pragma unroll
  for (int it = 0; it < 4; ++it) cvt8(k, Kb, tid + it * PREP_NTH);
  // V: 2,097,152 groups = 4 * PREP_NTH
  #pragma unroll
  for (int it = 0; it < 4; ++it) cvt8(v, Vb, tid + it * PREP_NTH);
  // W: 16,384 groups
  if (tid < 16384) cvt8(w, Wb, tid);
}

// ---------------------------------------------------------------------------
extern "C" void kernel_launch(void* const* d_in, const int* in_sizes, int n_in,
                              void* d_out, int out_size, void* d_ws, size_t ws_size,
                              hipStream_t stream)
{
  const float* keys    = (const float*)d_in[0];  // [B, NK, D]
  const float* queries = (const float*)d_in[1];  // [B, NQ, D]
  const float* values  = (const float*)d_in[2];  // [B, NK, V]
  const int*   mask    = (const int*)  d_in[3];  // [B, NQ, NK]
  const float* W       = (const float*)d_in[4];  // [O, V]
  const float* bias    = (const float*)d_in[5];  // [O]
  float* out = (float*)d_out;                    // [B, NQ, O]

  char* ws = (char*)d_ws;
  // layout (MiB): Qb 16 | Kb 32 | Vb 32 | Wb 1 | VWt 16 | P 64
  unsigned short* Qb  = (unsigned short*)(ws);
  unsigned short* Kb  = (unsigned short*)(ws + (16ull << 20));
  unsigned short* Vb  = (unsigned short*)(ws + (48ull << 20));
  unsigned short* Wb  = (unsigned short*)(ws + (80ull << 20));
  unsigned short* VWt = (unsigned short*)(ws + (81ull << 20));
  unsigned short* P   = (unsigned short*)(ws + (97ull << 20));

  prep_kernel<<<dim3(2048), 256, 0, stream>>>(queries, keys, values, W,
                                              Qb, Kb, Vb, Wb);
  qkvw_kernel<<<dim3(2560), 256, 0, stream>>>(Qb, Kb, Vb, Wb, mask, P, VWt);
  pvw_kernel<<<dim3(OO / 128, NQ / 32, BB), 256, 0, stream>>>(P, VWt, bias, out);
}

// Round 6
// 412.894 us; speedup vs baseline: 1.0515x; 1.0515x over previous
//
#include <hip/hip_runtime.h>

// Problem constants
#define BB   16
#define NQ   1024
#define NK   2048
#define DD   512
#define VV   512
#define OO   256
#define SCALE 0.044194173824159216f  // 1/sqrt(512)

typedef __attribute__((ext_vector_type(4))) float f32x4;
typedef __attribute__((ext_vector_type(8))) short s16x8;

#define AS1(p) ((const __attribute__((address_space(1))) void*)(p))
#define AS3(p) ((__attribute__((address_space(3))) void*)(p))

__device__ __forceinline__ unsigned short f2bf(float f) {
  unsigned u = __float_as_uint(f);
  u += 0x7fffu + ((u >> 16) & 1u);   // round-to-nearest-even (finite inputs)
  return (unsigned short)(u >> 16);
}
__device__ __forceinline__ float bf2f(unsigned short b) {
  return __uint_as_float(((unsigned)b) << 16);
}

#define MFMA16(a, b, c) __builtin_amdgcn_mfma_f32_16x16x32_bf16(a, b, c, 0, 0, 0)

// ---------------------------------------------------------------------------
// Core: C(128x128) = A(128xK) * B(128xK)^T in bf16 MFMA.
// R8: BK=64 (8 K-steps instead of 16 — halves barrier/drain count; the kernel
// is drain-latency-bound per R6/R7 counters). 128B LDS rows require the XOR
// swizzle (G4): inverse-swizzled GLOBAL source + swizzled ds_read, LDS dest
// linear (rule #21) — same scheme proven in pvw since R4. LDS 2x16KB = 32KB
// (fits inside the 34.8KB Cs allocation; occupancy unchanged vs BK=32).
// MFMA done in two ks-halves to keep only 8 live frags (VGPR control).
// ---------------------------------------------------------------------------
__device__ __forceinline__ void gemm_bt_core(
    const unsigned short* __restrict__ Abase,
    const unsigned short* __restrict__ Bbase,
    int K,
    unsigned short* As, unsigned short* Bs,   // [128*64] shorts each (16 KB)
    f32x4 acc[4][4])
{
  const int t = threadIdx.x;
  const int w = t >> 6;
  const int l = t & 63;
  const int wm = (w >> 1) * 64;
  const int wn = (w & 1) * 64;
  const int lm = l & 15;
  const int lq = l >> 4;
  const int srow = t >> 3;                         // 0..31 (stage row base)
  const int scol = (((t & 7) ^ (srow & 7)) << 3);  // swizzled source chunk (shorts)
  const int sdst = t * 8;                          // linear LDS dest (shorts)

  for (int kt = 0; kt < K; kt += 64) {
    #pragma unroll
    for (int i = 0; i < 4; ++i) {
      __builtin_amdgcn_global_load_lds(AS1(Abase + (size_t)(srow + i * 32) * K + kt + scol),
                                       AS3(As + i * 2048 + sdst), 16, 0, 0);
      __builtin_amdgcn_global_load_lds(AS1(Bbase + (size_t)(srow + i * 32) * K + kt + scol),
                                       AS3(Bs + i * 2048 + sdst), 16, 0, 0);
    }
    __syncthreads();
    #pragma unroll
    for (int ks = 0; ks < 2; ++ks) {
      s16x8 af[4], bfr[4];
      #pragma unroll
      for (int i = 0; i < 4; ++i) {
        const int ra = wm + i * 16 + lm;
        const int rb = wn + i * 16 + lm;
        af[i]  = *(const s16x8*)(As + ra * 64 + (((ks * 4 + lq) ^ (ra & 7)) << 3));
        bfr[i] = *(const s16x8*)(Bs + rb * 64 + (((ks * 4 + lq) ^ (rb & 7)) << 3));
      }
      #pragma unroll
      for (int mi = 0; mi < 4; ++mi)
        #pragma unroll
        for (int ni = 0; ni < 4; ++ni)
          acc[mi][ni] = MFMA16(af[mi], bfr[ni], acc[mi][ni]);
    }
    __syncthreads();
  }
}

// C/D layout (m89/m91): col = lane&15, row = (lane>>4)*4 + reg

#define CS_STRIDE 136   // shorts

// ---------------------------------------------------------------------------
// Merged kernel: blocks [0,2048) = QK tiles; blocks [2048,2560) = VW tiles:
// VWt[b,o,k] = sum_v V[b,k,v]*W[o,v] (transposed-epilogue NT GEMM).
// R6: XCD-chunked swizzle (2560 = 8 x 320, bijective); sums computed in pvw.
// R8: gemm_bt_core now BK=64 (Bs offset 8192).
// ---------------------------------------------------------------------------
__global__ __launch_bounds__(256)
void qkvw_kernel(const unsigned short* __restrict__ Qb,
                 const unsigned short* __restrict__ Kb,
                 const unsigned short* __restrict__ Vb,
                 const unsigned short* __restrict__ Wb,
                 const int* __restrict__ mask,
                 unsigned short* __restrict__ P,
                 unsigned short* __restrict__ VWt)
{
  __shared__ unsigned short smem[128 * CS_STRIDE];   // 34.8 KB
  unsigned short* As = smem;
  unsigned short* Bs = smem + 8192;
  unsigned short* Cs = smem;
  const int bid0 = blockIdx.x;
  const int bid = (bid0 & 7) * 320 + (bid0 >> 3);    // XCD-chunked swizzle
  const int t = threadIdx.x, w = t >> 6, l = t & 63;
  const int wm = (w >> 1) * 64, wn = (w & 1) * 64;
  const int lm = l & 15, lq = l >> 4;
  const int trow = t >> 4, tcol = (t & 15) * 8;

  f32x4 acc[4][4];
  #pragma unroll
  for (int i = 0; i < 4; ++i)
    #pragma unroll
    for (int j = 0; j < 4; ++j) acc[i][j] = (f32x4){0.f, 0.f, 0.f, 0.f};

  if (bid < 2048) {
    // ---------------- QK path ----------------
    const int b  = bid >> 7;
    const int tm = (bid >> 4) & 7;
    const int tn = bid & 15;

    gemm_bt_core(Qb + ((size_t)b * NQ + tm * 128) * DD,
                 Kb + ((size_t)b * NK + tn * 128) * DD, DD, As, Bs, acc);

    #pragma unroll
    for (int mi = 0; mi < 4; ++mi)
      #pragma unroll
      for (int ni = 0; ni < 4; ++ni)
        #pragma unroll
        for (int r = 0; r < 4; ++r)
          Cs[(wm + mi * 16 + lq * 4 + r) * CS_STRIDE + wn + ni * 16 + lm] =
              f2bf(acc[mi][ni][r] * SCALE);
    __syncthreads();

    #pragma unroll
    for (int it = 0; it < 8; ++it) {
      const int row = it * 16 + trow;
      const int gq = tm * 128 + row;
      const size_t gbase = ((size_t)b * NQ + gq) * NK + tn * 128 + tcol;
      s16x8 v = *(const s16x8*)(Cs + row * CS_STRIDE + tcol);
      const int4 m0 = *(const int4*)(mask + gbase);
      const int4 m1 = *(const int4*)(mask + gbase + 4);
      s16x8 o;
      o[0] = m0.x ? (short)f2bf(__expf(bf2f((unsigned short)v[0]))) : (short)0;
      o[1] = m0.y ? (short)f2bf(__expf(bf2f((unsigned short)v[1]))) : (short)0;
      o[2] = m0.z ? (short)f2bf(__expf(bf2f((unsigned short)v[2]))) : (short)0;
      o[3] = m0.w ? (short)f2bf(__expf(bf2f((unsigned short)v[3]))) : (short)0;
      o[4] = m1.x ? (short)f2bf(__expf(bf2f((unsigned short)v[4]))) : (short)0;
      o[5] = m1.y ? (short)f2bf(__expf(bf2f((unsigned short)v[5]))) : (short)0;
      o[6] = m1.z ? (short)f2bf(__expf(bf2f((unsigned short)v[6]))) : (short)0;
      o[7] = m1.w ? (short)f2bf(__expf(bf2f((unsigned short)v[7]))) : (short)0;
      *(s16x8*)(P + gbase) = o;
    }
  } else {
    // ---------------- VW path: VWt[b, o, k] ---------
    const int vid = bid - 2048;
    const int b  = vid >> 5;
    const int kt = (vid >> 1) & 15;
    const int ot = vid & 1;

    gemm_bt_core(Vb + ((size_t)b * NK + kt * 128) * VV,
                 Wb + (size_t)ot * 128 * VV, VV, As, Bs, acc);

    // C[r=k_local][c=o_local]; scatter transposed: Cs[o_local][k_local]
    #pragma unroll
    for (int mi = 0; mi < 4; ++mi)
      #pragma unroll
      for (int ni = 0; ni < 4; ++ni)
        #pragma unroll
        for (int r = 0; r < 4; ++r)
          Cs[(wn + ni * 16 + lm) * CS_STRIDE + wm + mi * 16 + lq * 4 + r] =
              f2bf(acc[mi][ni][r]);
    __syncthreads();

    #pragma unroll
    for (int it = 0; it < 8; ++it) {
      const int orow = it * 16 + trow;   // o_local
      s16x8 v = *(const s16x8*)(Cs + orow * CS_STRIDE + tcol);
      *(s16x8*)(VWt + ((size_t)b * OO + ot * 128 + orow) * NK + kt * 128 + tcol) = v;
    }
  }
}

// ---------------------------------------------------------------------------
// pvw: out[b,q,o] = (sum_k P[b,q,k] * VWt[b,o,k]) / (sum_k P[b,q,k]) + bias[o]
// R8: REVERTED to the R6 measured-best form (64q x 128o, 512 blocks, 48 KB,
// BK=64 dbuf prefetch, XOR swizzle, ones-MFMA row-sums). The R7 32q variant
// doubled VWt re-reads and regressed.
// ---------------------------------------------------------------------------
#define PW_STRIDE 132   // floats
__global__ __launch_bounds__(256)
void pvw_kernel(const unsigned short* __restrict__ P,
                const unsigned short* __restrict__ VWt,
                const float* __restrict__ bias,
                float* __restrict__ out)
{
  const int ot = blockIdx.x;   // 2
  const int qt = blockIdx.y;   // 16
  const int b  = blockIdx.z;   // 16
  __shared__ unsigned short smem[24576];   // 48 KB: 2 bufs x (A 64x64 + B 128x64)

  const int t = threadIdx.x, w = t >> 6, l = t & 63;
  const int wr = w >> 1, wc = w & 1;
  const int lm = l & 15, lq = l >> 4;

  f32x4 acc[2][4];
  #pragma unroll
  for (int i = 0; i < 2; ++i)
    #pragma unroll
    for (int j = 0; j < 4; ++j) acc[i][j] = (f32x4){0.f, 0.f, 0.f, 0.f};
  f32x4 accS[2];
  accS[0] = (f32x4){0.f, 0.f, 0.f, 0.f};
  accS[1] = (f32x4){0.f, 0.f, 0.f, 0.f};
  s16x8 ones;
  #pragma unroll
  for (int j = 0; j < 8; ++j) ones[j] = (short)0x3F80;   // bf16 1.0

  const unsigned short* Abase = P   + ((size_t)b * NQ + qt * 64) * NK;
  const unsigned short* Bbase = VWt + ((size_t)b * OO + ot * 128) * NK;

  // staging: thread t loads 16B chunk (t&7) of row (t>>3)+i*32; swizzled
  // source column = (chunk ^ (row&7)) so linear LDS dest holds swizzled data.
  const int srow = t >> 3;                               // 0..31
  const int ssc  = (((t & 7) ^ (srow & 7)) << 3);        // shorts

#define PV_STAGE(buf, k0v) do {                                                            \
    unsigned short* As_ = smem + (buf) * 12288;                                            \
    unsigned short* Bs_ = As_ + 4096;                                                      \
    const int k0_ = (k0v);                                                                 \
    __builtin_amdgcn_global_load_lds(AS1(Abase + (size_t)(srow     ) * NK + k0_ + ssc), AS3(As_ +        t * 8), 16, 0, 0); \
    __builtin_amdgcn_global_load_lds(AS1(Abase + (size_t)(srow + 32) * NK + k0_ + ssc), AS3(As_ + 2048 + t * 8), 16, 0, 0); \
    __builtin_amdgcn_global_load_lds(AS1(Bbase + (size_t)(srow     ) * NK + k0_ + ssc), AS3(Bs_ +        t * 8), 16, 0, 0); \
    __builtin_amdgcn_global_load_lds(AS1(Bbase + (size_t)(srow + 32) * NK + k0_ + ssc), AS3(Bs_ + 2048 + t * 8), 16, 0, 0); \
    __builtin_amdgcn_global_load_lds(AS1(Bbase + (size_t)(srow + 64) * NK + k0_ + ssc), AS3(Bs_ + 4096 + t * 8), 16, 0, 0); \
    __builtin_amdgcn_global_load_lds(AS1(Bbase + (size_t)(srow + 96) * NK + k0_ + ssc), AS3(Bs_ + 6144 + t * 8), 16, 0, 0); \
  } while (0)

  PV_STAGE(0, 0);
  __syncthreads();
  for (int k0 = 0; k0 < NK; k0 += 64) {
    const int cur = (k0 >> 6) & 1;
    if (k0 + 64 < NK) PV_STAGE(cur ^ 1, k0 + 64);      // prefetch overlaps compute
    const unsigned short* As = smem + cur * 12288;
    const unsigned short* Bs = As + 4096;
    s16x8 af[2][2], bfr[4][2];
    #pragma unroll
    for (int mi = 0; mi < 2; ++mi) {
      const int row = wr * 32 + mi * 16 + lm;
      #pragma unroll
      for (int ks = 0; ks < 2; ++ks)
        af[mi][ks] = *(const s16x8*)(As + row * 64 + (((ks * 4 + lq) ^ (row & 7)) << 3));
    }
    #pragma unroll
    for (int ni = 0; ni < 4; ++ni) {
      const int row = wc * 64 + ni * 16 + lm;
      #pragma unroll
      for (int ks = 0; ks < 2; ++ks)
        bfr[ni][ks] = *(const s16x8*)(Bs + row * 64 + (((ks * 4 + lq) ^ (row & 7)) << 3));
    }
    #pragma unroll
    for (int mi = 0; mi < 2; ++mi) {
      #pragma unroll
      for (int ni = 0; ni < 4; ++ni) {
        acc[mi][ni] = MFMA16(af[mi][0], bfr[ni][0], acc[mi][ni]);
        acc[mi][ni] = MFMA16(af[mi][1], bfr[ni][1], acc[mi][ni]);
      }
      accS[mi] = MFMA16(af[mi][0], ones, accS[mi]);    // row-sum (all cols equal)
      accS[mi] = MFMA16(af[mi][1], ones, accS[mi]);
    }
    __syncthreads();
  }
#undef PV_STAGE

  // epilogue: normalize in-register, via LDS, coalesced fp32 stores + bias
  float* Csf = (float*)smem;   // 64 x 132 floats = 33792 B <= 49152 B
  #pragma unroll
  for (int mi = 0; mi < 2; ++mi)
    #pragma unroll
    for (int r = 0; r < 4; ++r) {
      const float inv = 1.0f / accS[mi][r];
      const int row = wr * 32 + mi * 16 + lq * 4 + r;          // q_local
      #pragma unroll
      for (int ni = 0; ni < 4; ++ni) {
        const int col = wc * 64 + ni * 16 + lm;                // o_local
        Csf[row * PW_STRIDE + col] = acc[mi][ni][r] * inv;
      }
    }
  __syncthreads();
  const int trow = t >> 2;
  #pragma unroll
  for (int it = 0; it < 4; ++it) {
    const int col = (t & 3) * 8 + it * 32;
    f32x4 a = *(const f32x4*)(Csf + trow * PW_STRIDE + col);
    f32x4 c = *(const f32x4*)(Csf + trow * PW_STRIDE + col + 4);
    const int go = ot * 128 + col;
    a += *(const f32x4*)(bias + go);
    c += *(const f32x4*)(bias + go + 4);
    float* o = out + ((size_t)b * NQ + qt * 64 + trow) * OO + go;
    *(f32x4*)o = a;
    *(f32x4*)(o + 4) = c;
  }
}

// ---------------------------------------------------------------------------
// prep: fp32->bf16 converts (Q, K, V, W).
// R8: REVERTED to the R3 measured-best form (one 32B group/thread, 20544
// blocks). Both "optimized" variants (R5 4x-work, R7 grid-stride) regressed
// ~+20 us — the massively-parallel one-shot shape wins here. Do not touch.
// blocks: [0,4096) Q | [4096,12288) K | [12288,20480) V | [20480,20544) W
// ---------------------------------------------------------------------------
__device__ __forceinline__ void cvt8(const float* __restrict__ in,
                                     unsigned short* __restrict__ out, int i)
{
  const float4* p = (const float4*)in + (size_t)i * 2;
  const float4 a = p[0], b = p[1];
  s16x8 o;
  o[0] = (short)f2bf(a.x); o[1] = (short)f2bf(a.y);
  o[2] = (short)f2bf(a.z); o[3] = (short)f2bf(a.w);
  o[4] = (short)f2bf(b.x); o[5] = (short)f2bf(b.y);
  o[6] = (short)f2bf(b.z); o[7] = (short)f2bf(b.w);
  ((s16x8*)out)[i] = o;
}

__global__ __launch_bounds__(256)
void prep_kernel(const float* __restrict__ q, const float* __restrict__ k,
                 const float* __restrict__ v, const float* __restrict__ w,
                 unsigned short* __restrict__ Qb, unsigned short* __restrict__ Kb,
                 unsigned short* __restrict__ Vb, unsigned short* __restrict__ Wb)
{
  const int bid = blockIdx.x;
  const int t = threadIdx.x;
  if (bid < 4096) {
    cvt8(q, Qb, bid * 256 + t);
  } else if (bid < 12288) {
    cvt8(k, Kb, (bid - 4096) * 256 + t);
  } else if (bid < 20480) {
    cvt8(v, Vb, (bid - 12288) * 256 + t);
  } else {
    cvt8(w, Wb, (bid - 20480) * 256 + t);
  }
}

// ---------------------------------------------------------------------------
extern "C" void kernel_launch(void* const* d_in, const int* in_sizes, int n_in,
                              void* d_out, int out_size, void* d_ws, size_t ws_size,
                              hipStream_t stream)
{
  const float* keys    = (const float*)d_in[0];  // [B, NK, D]
  const float* queries = (const float*)d_in[1];  // [B, NQ, D]
  const float* values  = (const float*)d_in[2];  // [B, NK, V]
  const int*   mask    = (const int*)  d_in[3];  // [B, NQ, NK]
  const float* W       = (const float*)d_in[4];  // [O, V]
  const float* bias    = (const float*)d_in[5];  // [O]
  float* out = (float*)d_out;                    // [B, NQ, O]

  char* ws = (char*)d_ws;
  // layout (MiB): Qb 16 | Kb 32 | Vb 32 | Wb 1 | VWt 16 | P 64
  unsigned short* Qb  = (unsigned short*)(ws);
  unsigned short* Kb  = (unsigned short*)(ws + (16ull << 20));
  unsigned short* Vb  = (unsigned short*)(ws + (48ull << 20));
  unsigned short* Wb  = (unsigned short*)(ws + (80ull << 20));
  unsigned short* VWt = (unsigned short*)(ws + (81ull << 20));
  unsigned short* P   = (unsigned short*)(ws + (97ull << 20));

  prep_kernel<<<dim3(20544), 256, 0, stream>>>(queries, keys, values, W,
                                               Qb, Kb, Vb, Wb);
  qkvw_kernel<<<dim3(2560), 256, 0, stream>>>(Qb, Kb, Vb, Wb, mask, P, VWt);
  pvw_kernel<<<dim3(OO / 128, NQ / 64, BB), 256, 0, stream>>>(P, VWt, bias, out);
}